// Round 1
// baseline (10993.490 us; speedup 1.0000x reference)
//
#include <hip/hip_runtime.h>
#include <math.h>

#define S_LEN 4096
#define L_CH  12
#define CE    64
#define CHD   128
#define WE    256
#define HD    512
#define TAGS  64
#define GW    (4*HD)      // 2048
#define XDIM  (CHD+WE)    // 384
#define NBLK  32          // word-LSTM blocks: each owns 16 contiguous outputs = one 64B line

// ws layout (float offsets)
#define WS_GX    0
#define WS_CREP  (WS_GX   + (size_t)S_LEN*GW)      // 8,388,608 floats
#define WS_HEXT  (WS_CREP + (size_t)S_LEN*CHD)     // +524,288
// hext: (S_LEN+1) rows x HD. Row r = h_{r-1} + 2.0 (row 0 = hx0+2).
// Rows 1..S_LEN double as `outs` (+2 bias) for k_out.

typedef float v4f __attribute__((ext_vector_type(4)));

static __device__ __forceinline__ float sigf(float x) {
    return 1.0f / (1.0f + __expf(-x));
}
static __device__ __forceinline__ float tanhfast(float x) {
    return 1.0f - 2.0f / (__expf(2.0f * x) + 1.0f);
}
static __device__ __forceinline__ float dot4(v4f a, v4f b) {
    return a.x*b.x + a.y*b.y + a.z*b.z + a.w*b.w;
}
// DPP-assisted partial-sum step: a += dpp_move(a). Masked-off rows add 0.
template <int CTRL, int RMASK>
static __device__ __forceinline__ float dpp_add(float a) {
    int t = __builtin_amdgcn_update_dpp(0, __float_as_int(a), CTRL, RMASK, 0xf, true);
    return a + __int_as_float(t);
}
static __device__ __forceinline__ float rdlane(float v, int l) {
    return __int_as_float(__builtin_amdgcn_readlane(__float_as_int(v), l));
}

// ---------------------------------------------------------------------------
// K_init: hext row 0 = hx0 + 2, rows 1..S_LEN = 0, stores bypassing L1/L2
// (sc0 sc1) so readiness state lives at MALL from the start.
// ---------------------------------------------------------------------------
__global__ __launch_bounds__(256) void k_init(const float* __restrict__ hx0,
                                              float* __restrict__ hext) {
    size_t i = ((size_t)blockIdx.x * 256 + threadIdx.x) * 4;
    if (i >= (size_t)(S_LEN + 1) * HD) return;
    v4f v;
    if (i < HD) {
        v.x = hx0[i+0] + 2.0f; v.y = hx0[i+1] + 2.0f;
        v.z = hx0[i+2] + 2.0f; v.w = hx0[i+3] + 2.0f;
    } else {
        v.x = 0.f; v.y = 0.f; v.z = 0.f; v.w = 0.f;
    }
    float* p = hext + i;
    asm volatile("global_store_dwordx4 %0, %1, off sc0 sc1"
                 :: "v"(p), "v"(v) : "memory");
}

// ---------------------------------------------------------------------------
// K1: char LSTM. 256 blocks x 256 threads; block owns 16 words, runs 12 steps.
// ---------------------------------------------------------------------------
__global__ __launch_bounds__(256) void k_char_lstm(
    const int* __restrict__ c_seq, const float* __restrict__ char_emb,
    const float* __restrict__ c_hx0, const float* __restrict__ c_cx0,
    const float* __restrict__ Wih1, const float* __restrict__ Whh1,
    const float* __restrict__ bih1, const float* __restrict__ bhh1,
    float* __restrict__ char_rep)
{
    __shared__ float xs[16][CE + 4];
    __shared__ float hs[16][CHD + 4];
    __shared__ float cs[16][CHD + 4];
    __shared__ float gs[16][4*CHD + 4];
    const int tid = threadIdx.x;
    const int w0  = blockIdx.x * 16;

    for (int u = tid; u < 16*CHD; u += 256) {
        int w = u >> 7, k = u & (CHD-1);
        hs[w][k] = c_hx0[k];
        cs[w][k] = c_cx0[k];
    }
    __syncthreads();

    const int wg = tid & 3;
    const int rg = tid >> 2;
    const int uw = tid >> 4;
    const int uj = (tid & 15) * 8;

    for (int t = 0; t < L_CH; ++t) {
        {
            int w = tid >> 4, k4 = (tid & 15) * 4;
            int ci = c_seq[(w0 + w) * L_CH + t];
            float4 v = *(const float4*)(char_emb + (size_t)ci * CE + k4);
            *(float4*)&xs[w][k4] = v;
        }
        __syncthreads();

        float acc[8][4];
        #pragma unroll
        for (int i = 0; i < 8; ++i)
            #pragma unroll
            for (int j = 0; j < 4; ++j) acc[i][j] = 0.0f;

        for (int kc = 0; kc < CE/4; ++kc) {
            int k = kc * 4;
            float4 xv[4];
            #pragma unroll
            for (int j = 0; j < 4; ++j) xv[j] = *(const float4*)&xs[wg*4 + j][k];
            #pragma unroll
            for (int i = 0; i < 8; ++i) {
                int r = rg*8 + i;
                float4 wv = *(const float4*)(Wih1 + (size_t)r*CE + k);
                #pragma unroll
                for (int j = 0; j < 4; ++j)
                    acc[i][j] += wv.x*xv[j].x + wv.y*xv[j].y + wv.z*xv[j].z + wv.w*xv[j].w;
            }
        }
        for (int kc = 0; kc < CHD/4; ++kc) {
            int k = kc * 4;
            float4 hv[4];
            #pragma unroll
            for (int j = 0; j < 4; ++j) hv[j] = *(const float4*)&hs[wg*4 + j][k];
            #pragma unroll
            for (int i = 0; i < 8; ++i) {
                int r = rg*8 + i;
                float4 wv = *(const float4*)(Whh1 + (size_t)r*CHD + k);
                #pragma unroll
                for (int j = 0; j < 4; ++j)
                    acc[i][j] += wv.x*hv[j].x + wv.y*hv[j].y + wv.z*hv[j].z + wv.w*hv[j].w;
            }
        }
        #pragma unroll
        for (int i = 0; i < 8; ++i) {
            int r = rg*8 + i;
            float b = bih1[r] + bhh1[r];
            #pragma unroll
            for (int j = 0; j < 4; ++j) gs[wg*4 + j][r] = acc[i][j] + b;
        }
        __syncthreads();

        #pragma unroll
        for (int i = 0; i < 8; ++i) {
            int j = uj + i;
            float gi = gs[uw][j];
            float gf = gs[uw][CHD + j];
            float gg = gs[uw][2*CHD + j];
            float go = gs[uw][3*CHD + j];
            float c = sigf(gf)*cs[uw][j] + sigf(gi)*tanhfast(gg);
            cs[uw][j] = c;
            hs[uw][j] = sigf(go)*tanhfast(c);
        }
        __syncthreads();
    }
    #pragma unroll
    for (int i4 = 0; i4 < 2; ++i4) {
        float4 v;
        v.x = hs[uw][uj + i4*4 + 0]; v.y = hs[uw][uj + i4*4 + 1];
        v.z = hs[uw][uj + i4*4 + 2]; v.w = hs[uw][uj + i4*4 + 3];
        *(float4*)(char_rep + (size_t)(w0 + uw)*CHD + uj + i4*4) = v;
    }
}

// ---------------------------------------------------------------------------
// K2: Gx[t][2048] = concat(char_rep, wv)[t] @ Wih2^T + (bih2+bhh2)
// ---------------------------------------------------------------------------
__global__ __launch_bounds__(256) void k_gx(
    const int* __restrict__ w_seq, const float* __restrict__ word_emb,
    const float* __restrict__ char_rep,
    const float* __restrict__ Wih2, const float* __restrict__ bih2,
    const float* __restrict__ bhh2, float* __restrict__ Gx)
{
    __shared__ float xs[16][XDIM + 4];
    const int tid = threadIdx.x;
    const int w0  = blockIdx.x * 16;
    const int slice = blockIdx.y;

    {
        int w = tid >> 4, seg = tid & 15;
        int wsq = w_seq[w0 + w];
        #pragma unroll
        for (int i4 = 0; i4 < 6; ++i4) {
            int k = seg*24 + i4*4;
            float4 v;
            if (k < CHD) v = *(const float4*)(char_rep + (size_t)(w0+w)*CHD + k);
            else         v = *(const float4*)(word_emb + (size_t)wsq*WE + (k - CHD));
            *(float4*)&xs[w][k] = v;
        }
    }
    __syncthreads();

    const int wg = tid & 3, rg = tid >> 2;
    float acc[8][4];
    #pragma unroll
    for (int i = 0; i < 8; ++i)
        #pragma unroll
        for (int j = 0; j < 4; ++j) acc[i][j] = 0.0f;

    for (int kc = 0; kc < XDIM/4; ++kc) {
        int k = kc * 4;
        float4 xv[4];
        #pragma unroll
        for (int j = 0; j < 4; ++j) xv[j] = *(const float4*)&xs[wg*4 + j][k];
        #pragma unroll
        for (int i = 0; i < 8; ++i) {
            int r = slice*512 + rg*8 + i;
            float4 wv = *(const float4*)(Wih2 + (size_t)r*XDIM + k);
            #pragma unroll
            for (int j = 0; j < 4; ++j)
                acc[i][j] += wv.x*xv[j].x + wv.y*xv[j].y + wv.z*xv[j].z + wv.w*xv[j].w;
        }
    }
    #pragma unroll
    for (int i = 0; i < 8; ++i) {
        int r = slice*512 + rg*8 + i;
        float b = bih2[r] + bhh2[r];
        #pragma unroll
        for (int j = 0; j < 4; ++j)
            Gx[(size_t)(w0 + wg*4 + j)*GW + r] = acc[i][j] + b;
    }
}

// ---------------------------------------------------------------------------
// K3: sequential word LSTM with LINE-ATOMIC h broadcast.
// 32 blocks x 256 threads (4 waves). Block b owns outputs [b*16, b*16+16) =
// exactly ONE 64B cache line of each hext row. Wave w owns 4 contiguous
// outputs jo4 = b*16 + w*4 .. +3 (all 4 gates each).
// Lane: gate-pair g2 = lane>>5 (gates 2*g2, 2*g2+1), k-slice kk=(lane&31)*16.
// Per lane: 8 gate-rows x 16 weights (128 floats, asm-loaded -> remat-proof).
// Step t: poll hext row t (4x dwordx4 sc0 sc1; ready iff all values > 0.5,
// stored as h+2), 8 dot-slices, 8x 32-lane DPP row-reduce, 16 readlanes ->
// wave-uniform gate sums, gates computed redundantly by all lanes, h+2 values
// aggregated in LDS, barrier, then wave 0 lanes 0..15 emit ONE coalesced 64B
// store sc0 sc1. Each line is written exactly once per step -> pollers see
// all-zero or final (no partial-line coherence bounces). Write-once rows =>
// no fences needed; hsh double-buffered on t&1 (poll of row t+1 orders reuse).
// ---------------------------------------------------------------------------
__global__ __launch_bounds__(256, 1) void k_word_lstm(
    const float* __restrict__ Gx, const float* __restrict__ Whh2,
    const float* __restrict__ cx0, float* __restrict__ hext)
{
    __shared__ __align__(16) float hsh[2][16];
    const int tid  = threadIdx.x;
    const int w    = tid >> 6;             // wave 0..3
    const int lane = tid & 63;
    const int jb   = blockIdx.x * 16;      // block's 16-output line
    const int jo4  = jb + w * 4;           // wave's 4 outputs
    const int g2   = lane >> 5;            // gate pair: gates 2*g2, 2*g2+1
    const int qe   = g2 * 2, qo = qe + 1;
    const int kk   = (lane & 31) * 16;     // k-slice of 16

    // weights via asm volatile (opaque to remat): 4 outputs x 2 gates x 16.
    v4f we_[4][4], wo_[4][4];
    float wse[4], wso[4];
    #pragma unroll
    for (int o = 0; o < 4; ++o) {
        const float* pe = Whh2 + (size_t)(qe*HD + jo4 + o)*HD + kk;
        const float* po = Whh2 + (size_t)(qo*HD + jo4 + o)*HD + kk;
        asm volatile(
            "global_load_dwordx4 %0, %8, off\n\t"
            "global_load_dwordx4 %1, %8, off offset:16\n\t"
            "global_load_dwordx4 %2, %8, off offset:32\n\t"
            "global_load_dwordx4 %3, %8, off offset:48\n\t"
            "global_load_dwordx4 %4, %9, off\n\t"
            "global_load_dwordx4 %5, %9, off offset:16\n\t"
            "global_load_dwordx4 %6, %9, off offset:32\n\t"
            "global_load_dwordx4 %7, %9, off offset:48\n\t"
            "s_waitcnt vmcnt(0)"
            : "=&v"(we_[o][0]), "=&v"(we_[o][1]), "=&v"(we_[o][2]), "=&v"(we_[o][3]),
              "=&v"(wo_[o][0]), "=&v"(wo_[o][1]), "=&v"(wo_[o][2]), "=&v"(wo_[o][3])
            : "v"(pe), "v"(po));
        wse[o] = 2.0f * (we_[o][0].x+we_[o][0].y+we_[o][0].z+we_[o][0].w
                       + we_[o][1].x+we_[o][1].y+we_[o][1].z+we_[o][1].w
                       + we_[o][2].x+we_[o][2].y+we_[o][2].z+we_[o][2].w
                       + we_[o][3].x+we_[o][3].y+we_[o][3].z+we_[o][3].w);
        wso[o] = 2.0f * (wo_[o][0].x+wo_[o][0].y+wo_[o][0].z+wo_[o][0].w
                       + wo_[o][1].x+wo_[o][1].y+wo_[o][1].z+wo_[o][1].w
                       + wo_[o][2].x+wo_[o][2].y+wo_[o][2].z+wo_[o][2].w
                       + wo_[o][3].x+wo_[o][3].y+wo_[o][3].z+wo_[o][3].w);
    }

    float creg[4];
    #pragma unroll
    for (int o = 0; o < 4; ++o) creg[o] = cx0[jo4 + o];   // uniform across wave

    for (int t = 0; t < S_LEN; ++t) {
        // Gx prefetch: 4x dwordx4 (wave owns contiguous j) issued before poll.
        const float* gp = Gx + (size_t)t*GW + jo4;
        float gxa[4][4];
        {
            float4 v0 = *(const float4*)(gp);
            float4 v1 = *(const float4*)(gp + HD);
            float4 v2 = *(const float4*)(gp + 2*HD);
            float4 v3 = *(const float4*)(gp + 3*HD);
            gxa[0][0]=v0.x; gxa[0][1]=v0.y; gxa[0][2]=v0.z; gxa[0][3]=v0.w;
            gxa[1][0]=v1.x; gxa[1][1]=v1.y; gxa[1][2]=v1.z; gxa[1][3]=v1.w;
            gxa[2][0]=v2.x; gxa[2][1]=v2.y; gxa[2][2]=v2.z; gxa[2][3]=v2.w;
            gxa[3][0]=v3.x; gxa[3][1]=v3.y; gxa[3][2]=v3.z; gxa[3][3]=v3.w;
        }

        const float* hsrc = hext + (size_t)t*HD + kk;
        v4f r0, r1, r2, r3;
        for (;;) {
            asm volatile(
                "global_load_dwordx4 %0, %4, off sc0 sc1\n\t"
                "global_load_dwordx4 %1, %4, off offset:16 sc0 sc1\n\t"
                "global_load_dwordx4 %2, %4, off offset:32 sc0 sc1\n\t"
                "global_load_dwordx4 %3, %4, off offset:48 sc0 sc1\n\t"
                "s_waitcnt vmcnt(0)"
                : "=&v"(r0), "=&v"(r1), "=&v"(r2), "=&v"(r3)
                : "v"(hsrc)
                : "memory");
            float mn = fminf(fminf(fminf(r0.x, r0.y), fminf(r0.z, r0.w)),
                             fminf(fminf(r1.x, r1.y), fminf(r1.z, r1.w)));
            mn = fminf(mn, fminf(fminf(fminf(r2.x, r2.y), fminf(r2.z, r2.w)),
                                 fminf(fminf(r3.x, r3.y), fminf(r3.z, r3.w))));
            if (__all(mn > 0.5f)) break;
        }

        // matvec on (h+2), fold out the +2 via wsum; 8 rows per lane.
        float ae[4], ao[4];
        #pragma unroll
        for (int o = 0; o < 4; ++o) {
            ae[o] = dot4(we_[o][0], r0) + dot4(we_[o][1], r1)
                  + dot4(we_[o][2], r2) + dot4(we_[o][3], r3) - wse[o];
            ao[o] = dot4(wo_[o][0], r0) + dot4(wo_[o][1], r1)
                  + dot4(wo_[o][2], r2) + dot4(wo_[o][3], r3) - wso[o];
        }

        // 32-lane DPP reduce x8: lane31 = sum(0..31), lane63 = sum(32..63)
        #pragma unroll
        for (int o = 0; o < 4; ++o) {
            ae[o] = dpp_add<0x111, 0xf>(ae[o]); ao[o] = dpp_add<0x111, 0xf>(ao[o]);
            ae[o] = dpp_add<0x112, 0xf>(ae[o]); ao[o] = dpp_add<0x112, 0xf>(ao[o]);
            ae[o] = dpp_add<0x114, 0xf>(ae[o]); ao[o] = dpp_add<0x114, 0xf>(ao[o]);
            ae[o] = dpp_add<0x118, 0xf>(ae[o]); ao[o] = dpp_add<0x118, 0xf>(ao[o]);
            ae[o] = dpp_add<0x142, 0xa>(ae[o]); ao[o] = dpp_add<0x142, 0xa>(ao[o]);
        }

        // gate sums, wave-uniform (i,f from half 0; g,o from half 1)
        float hn[4];
        #pragma unroll
        for (int o = 0; o < 4; ++o) {
            float si = rdlane(ae[o], 31), sf = rdlane(ao[o], 31);
            float sg = rdlane(ae[o], 63), so = rdlane(ao[o], 63);
            float g0 = gxa[0][o] + si;
            float g1 = gxa[1][o] + sf;
            float g2v = gxa[2][o] + sg;
            float g3 = gxa[3][o] + so;
            float c  = sigf(g1)*creg[o] + sigf(g0)*tanhfast(g2v);
            creg[o] = c;
            hn[o] = sigf(g3)*tanhfast(c) + 2.0f;
        }

        // aggregate the block's 16 outputs, then ONE 64B line store.
        if (lane == 0) {
            float4 hv; hv.x = hn[0]; hv.y = hn[1]; hv.z = hn[2]; hv.w = hn[3];
            *(float4*)&hsh[t & 1][w*4] = hv;
        }
        __syncthreads();
        if (tid < 16) {
            float v = hsh[t & 1][tid];
            float* dst = hext + (size_t)(t+1)*HD + jb + tid;
            asm volatile("global_store_dword %0, %1, off sc0 sc1"
                         :: "v"(dst), "v"(v) : "memory");
        }
    }
}

// ---------------------------------------------------------------------------
// K4: tag projection + log_softmax. Reads hext rows 1..S_LEN (+2 bias).
// ---------------------------------------------------------------------------
__global__ __launch_bounds__(256) void k_out(
    const float* __restrict__ outs_b, const float* __restrict__ W_out,
    const float* __restrict__ b_out, float* __restrict__ out)
{
    __shared__ float hh[16][HD + 4];
    __shared__ float ts[16][TAGS + 4];
    __shared__ float lse[16];
    const int tid = threadIdx.x;
    const int w0  = blockIdx.x * 16;

    {
        int w = tid >> 4, k0 = (tid & 15) * 32;
        #pragma unroll
        for (int i4 = 0; i4 < 8; ++i4) {
            float4 v = *(const float4*)(outs_b + (size_t)(w0+w)*HD + k0 + i4*4);
            int k = k0 + i4*4;
            hh[w][k+0] = v.x - 2.0f; hh[w][k+1] = v.y - 2.0f;
            hh[w][k+2] = v.z - 2.0f; hh[w][k+3] = v.w - 2.0f;
        }
    }
    __syncthreads();

    const int tag = tid & 63;
    const int wg  = tid >> 6;
    float a0 = 0.f, a1 = 0.f, a2 = 0.f, a3 = 0.f;
    for (int kc = 0; kc < HD/4; ++kc) {
        int k = kc * 4;
        float4 wv = *(const float4*)(W_out + (size_t)tag*HD + k);
        float4 x0 = *(const float4*)&hh[wg*4+0][k];
        float4 x1 = *(const float4*)&hh[wg*4+1][k];
        float4 x2 = *(const float4*)&hh[wg*4+2][k];
        float4 x3 = *(const float4*)&hh[wg*4+3][k];
        a0 += wv.x*x0.x + wv.y*x0.y + wv.z*x0.z + wv.w*x0.w;
        a1 += wv.x*x1.x + wv.y*x1.y + wv.z*x1.z + wv.w*x1.w;
        a2 += wv.x*x2.x + wv.y*x2.y + wv.z*x2.z + wv.w*x2.w;
        a3 += wv.x*x3.x + wv.y*x3.y + wv.z*x3.z + wv.w*x3.w;
    }
    float bo = b_out[tag];
    ts[wg*4+0][tag] = a0 + bo;
    ts[wg*4+1][tag] = a1 + bo;
    ts[wg*4+2][tag] = a2 + bo;
    ts[wg*4+3][tag] = a3 + bo;
    __syncthreads();

    if (tid < 16) {
        float m = -1e30f;
        for (int q = 0; q < TAGS; ++q) m = fmaxf(m, ts[tid][q]);
        float ssum = 0.0f;
        for (int q = 0; q < TAGS; ++q) ssum += __expf(ts[tid][q] - m);
        lse[tid] = m + __logf(ssum);
    }
    __syncthreads();

    #pragma unroll
    for (int jjj = 0; jjj < 4; ++jjj)
        out[(size_t)(w0 + wg*4 + jjj)*TAGS + tag] = ts[wg*4+jjj][tag] - lse[wg*4+jjj];
}

// ---------------------------------------------------------------------------
extern "C" void kernel_launch(void* const* d_in, const int* in_sizes, int n_in,
                              void* d_out, int out_size, void* d_ws, size_t ws_size,
                              hipStream_t stream) {
    (void)in_sizes; (void)n_in; (void)out_size; (void)ws_size;
    const int*   w_seq    = (const int*)  d_in[0];
    const int*   c_seq    = (const int*)  d_in[1];
    const float* char_emb = (const float*)d_in[2];
    const float* word_emb = (const float*)d_in[3];
    const float* c_hx0    = (const float*)d_in[4];
    const float* c_cx0    = (const float*)d_in[5];
    const float* hx0      = (const float*)d_in[6];
    const float* cx0      = (const float*)d_in[7];
    const float* Wih1     = (const float*)d_in[8];
    const float* Whh1     = (const float*)d_in[9];
    const float* bih1     = (const float*)d_in[10];
    const float* bhh1     = (const float*)d_in[11];
    const float* Wih2     = (const float*)d_in[12];
    const float* Whh2     = (const float*)d_in[13];
    const float* bih2     = (const float*)d_in[14];
    const float* bhh2     = (const float*)d_in[15];
    const float* W_out    = (const float*)d_in[16];
    const float* b_out    = (const float*)d_in[17];

    float* ws   = (float*)d_ws;
    float* Gx   = ws + WS_GX;
    float* crep = ws + WS_CREP;
    float* hext = ws + WS_HEXT;

    int init_blocks = (int)(((size_t)(S_LEN + 1) * HD / 4 + 255) / 256);
    hipLaunchKernelGGL(k_init, dim3(init_blocks), dim3(256), 0, stream, hx0, hext);
    hipLaunchKernelGGL(k_char_lstm, dim3(256), dim3(256), 0, stream,
                       c_seq, char_emb, c_hx0, c_cx0, Wih1, Whh1, bih1, bhh1, crep);
    hipLaunchKernelGGL(k_gx, dim3(256, 4), dim3(256), 0, stream,
                       w_seq, word_emb, crep, Wih2, bih2, bhh2, Gx);
    hipLaunchKernelGGL(k_word_lstm, dim3(NBLK), dim3(256), 0, stream,
                       Gx, Whh2, cx0, hext);
    hipLaunchKernelGGL(k_out, dim3(256), dim3(256), 0, stream,
                       hext + HD, W_out, b_out, (float*)d_out);
}